// Round 8
// baseline (613.707 us; speedup 1.0000x reference)
//
#include <hip/hip_runtime.h>
#include <hip/hip_bf16.h>
#include <hip/hip_cooperative_groups.h>

// GAT on two 512-node cliques + bipartite cross edges, 5 GATConv layers.
//
// R21 = R20's fused persistent kernel (phase bodies byte-identical,
// absmax 0.0 verified) with ALL hand-rolled barrier machinery replaced by
// the sanctioned runtime mechanism: hipLaunchCooperativeKernel +
// cooperative_groups::this_grid().sync().
// Why: four hand-rolled barrier variants all failed on CDNA4's coherence
// model -- R14 ACQ_REL single-line (46us/barrier), R18 ACQUIRE polls
// (buffer_inv per poll -> 580MB HBM), R19 RELAXED polls (stale local-XCD
// L2 -> hang), R20 RMW-only polls (same-line RMWs serialize at the
// device-coherent point -> ~90us/barrier + 41ms contention outlier).
// Measured phase work is only ~30-60us total; the runtime's grid sync
// (__ockl_grid_sync) is the remaining candidate for a fast barrier.

namespace cg = cooperative_groups;

typedef __hip_bfloat16 bf16;

__device__ __forceinline__ float b2f(bf16 x) { return __bfloat162float(x); }

__device__ __forceinline__ int detect_bf16(const void* desc1) {
  const unsigned* u = (const unsigned*)desc1;
  int hits = 0;
#pragma unroll 8
  for (int i = 0; i < 256; ++i) {
    unsigned e = (u[i] >> 7) & 0xFFu;
    hits += (e >= 100u && e <= 140u) ? 1 : 0;
  }
  return hits >= 200 ? 1 : 0;
}

__device__ __forceinline__ float load_in(const void* p, int i, int bf) {
  return bf ? b2f(((const bf16*)p)[i]) : ((const float*)p)[i];
}

// ------------------------------------------------------- GAT layer phase ----
// block = (S<<7)|hd, 512 threads.  Phase A: per-thread node dot from planar
// xt (coalesced per k) with W column in LDS; FMA parity order identical to
// the verified kernels (k even->acc0, odd->acc1).  Phase B: R13 bucket
// softmax VERBATIM.  Output written planar (coalesced).
template <int CROSS>
__device__ __forceinline__ void layer_phase(
    char* smem, float* wcol, const float* __restrict__ xt_in,
    float* __restrict__ xt_out, const float* __restrict__ W1t,
    const float* __restrict__ vecs, int bid) {
  float*    sS      = (float*)(smem);            // 512 f
  float*    sH      = (float*)(smem + 2048);     // 512 f
  unsigned* hA      = (unsigned*)(smem + 4096);  // 512 u
  unsigned* ISb     = (unsigned*)(smem + 6144);  // 512 u
  unsigned* binNext = (unsigned*)(smem + 8192);  // 512 u
  float2*   PRE     = (float2*)(smem + 10240);   // 512 f2
  float2*   SUF     = (float2*)(smem + 14336);   // 512 f2
  float*    red     = (float*)(smem + 18432);    // 16 f
  unsigned* wTot    = (unsigned*)(smem + 18496); // 8 u
  float2*   preTot  = (float2*)(smem + 18528);   // 8 f2
  float2*   sufTot  = (float2*)(smem + 18592);   // 8 f2

  const int tid  = threadIdx.x;
  const int lane = tid & 63;
  const int wave = tid >> 6;
  const int hd   = bid & 127;
  const int S    = bid >> 7;
  const int D    = CROSS ? (1 - S) : S;
  const float a_src = vecs[hd], a_dst = vecs[128 + hd], bias = vecs[256 + hd];

  // Phase A: stage W column, per-thread dot(s).
  if (tid < 32) ((float4*)wcol)[tid] = ((const float4*)(W1t + hd * 128))[tid];
  __syncthreads();
  float acc0 = 0.f, acc1 = 0.f, accD0 = 0.f, accD1 = 0.f;
  {
    const int nS = S * 512 + tid;
    const int nD = D * 512 + tid;
    for (int k0 = 0; k0 < 128; k0 += 8) {
      float xs[8], xd[8];
#pragma unroll
      for (int u = 0; u < 8; ++u) {
        xs[u] = xt_in[(k0 + u) * 1024 + nS];
        if (CROSS) xd[u] = xt_in[(k0 + u) * 1024 + nD];
      }
#pragma unroll
      for (int u = 0; u < 8; u += 2) {
        acc0 = fmaf(xs[u],     wcol[k0 + u],     acc0);
        acc1 = fmaf(xs[u + 1], wcol[k0 + u + 1], acc1);
        if (CROSS) {
          accD0 = fmaf(xd[u],     wcol[k0 + u],     accD0);
          accD1 = fmaf(xd[u + 1], wcol[k0 + u + 1], accD1);
        }
      }
    }
  }
  const float h_src = acc0 + acc1;
  const float h_dst = CROSS ? (accD0 + accD1) : h_src;
  const float s_own = h_src * a_src;
  const float d_own = h_dst * a_dst;

  // B1: block min/max of s; zero hist.
  {
    float mnw = s_own, mxw = s_own;
#pragma unroll
    for (int off = 32; off > 0; off >>= 1) {
      mnw = fminf(mnw, __shfl_down(mnw, off));
      mxw = fmaxf(mxw, __shfl_down(mxw, off));
    }
    if (lane == 0) { red[wave] = mnw; red[8 + wave] = mxw; }
  }
  hA[tid] = 0;
  binNext[tid] = 0;
  __syncthreads();                                        // (1)
  const float mn = fminf(fminf(fminf(red[0], red[1]), fminf(red[2], red[3])),
                         fminf(fminf(red[4], red[5]), fminf(red[6], red[7])));
  const float mx = fmaxf(fmaxf(fmaxf(red[8], red[9]), fmaxf(red[10], red[11])),
                         fmaxf(fmaxf(red[12], red[13]), fmaxf(red[14], red[15])));
  const float scale = 512.0f / fmaxf(mx - mn, 1e-20f);

  // B2: histogram.
  const int myBin = (int)fminf(fmaxf((s_own - mn) * scale, 0.0f), 511.0f);
  atomicAdd(&hA[myBin], 1u);
  __syncthreads();                                        // (2)

  // B3: inclusive scan of hist.
  {
    unsigned v = hA[tid];
#pragma unroll
    for (int off = 1; off < 64; off <<= 1) {
      unsigned u = __shfl_up(v, off);
      if (lane >= off) v += u;
    }
    if (lane == 63) wTot[wave] = v;
    __syncthreads();                                      // (3)
    unsigned pre = 0;
#pragma unroll
    for (int w = 0; w < 8; ++w) pre += (w < wave) ? wTot[w] : 0u;
    ISb[tid] = v + pre;
    __syncthreads();                                      // (4)
  }

  // B4: scatter into bucket order.
  {
    unsigned base = myBin ? ISb[myBin - 1] : 0u;
    unsigned pos = base + atomicAdd(&binNext[myBin], 1u);
    sS[pos] = s_own;
    sH[pos] = h_src;
  }
  __syncthreads();                                        // (5)

  // B5: prefix/suffix pairs.
  {
    const float sv = sS[tid];
    const float hv = sH[tid];
    const float e1 = __expf(sv), e2 = __expf(0.2f * sv);
    float p0 = e2, p1 = e2 * hv;
    float q0 = e1, q1 = e1 * hv;
#pragma unroll
    for (int off = 1; off < 64; off <<= 1) {
      float u0 = __shfl_up(p0, off), u1 = __shfl_up(p1, off);
      if (lane >= off) { p0 += u0; p1 += u1; }
      float v0 = __shfl_down(q0, off), v1 = __shfl_down(q1, off);
      if (lane + off < 64) { q0 += v0; q1 += v1; }
    }
    if (lane == 63) preTot[wave] = make_float2(p0, p1);
    if (lane == 0)  sufTot[wave] = make_float2(q0, q1);
    __syncthreads();                                      // (6)
    float a0 = 0.f, a1 = 0.f, b0 = 0.f, b1 = 0.f;
#pragma unroll
    for (int w = 0; w < 8; ++w) {
      float2 pt = preTot[w], st = sufTot[w];
      if (w < wave) { a0 += pt.x; a1 += pt.y; }
      if (w > wave) { b0 += st.x; b1 += st.y; }
    }
    PRE[tid] = make_float2(p0 + a0, p1 + a1);
    SUF[tid] = make_float2(q0 + b0, q1 + b1);
    __syncthreads();                                      // (7)
  }

  // B7: per destination combine.
  {
    const float theta = -d_own;
    int b = (int)fminf(fmaxf((theta - mn) * scale, 0.0f), 511.0f);
    unsigned k0 = b ? ISb[b - 1] : 0u;
    unsigned k1 = ISb[b];
    float F1 = __expf(d_own), F2 = __expf(0.2f * d_own);
    float P2 = 0.f, P2h = 0.f, S1 = 0.f, S1h = 0.f;
    if (k0 > 0)   { float2 t2 = PRE[k0 - 1]; P2 = t2.x; P2h = t2.y; }
    if (k1 < 512) { float2 t2 = SUF[k1];     S1 = t2.x; S1h = t2.y; }
    float den = F1 * S1 + F2 * P2;
    float num = F1 * S1h + F2 * P2h;
    for (unsigned e = k0; e < k1; ++e) {
      float se = sS[e], he = sH[e];
      float p = (se >= theta) ? F1 * __expf(se) : F2 * __expf(0.2f * se);
      den += p;
      num = fmaf(p, he, num);
    }
    if (CROSS) {
      float t = h_dst * a_src + d_own;
      float p = __expf(fmaxf(t, 0.2f * t));
      den += p;
      num = fmaf(p, h_dst, num);
    }
    float o = num / (den + 1e-16f) + bias;
    o = (o > 0.f) ? o : expm1f(o);  // ELU
    xt_out[hd * 1024 + D * 512 + tid] = o;  // planar, coalesced
  }
}

// ------------------------------------------------------ fused cooperative ----
__global__ __launch_bounds__(512, 2) void fused_kernel(
    const void* __restrict__ desc1, const void* __restrict__ desc2,
    const void* __restrict__ W1,   const void* __restrict__ as1,
    const void* __restrict__ ad1,  const void* __restrict__ b1,
    const void* __restrict__ W2,   const void* __restrict__ as2,
    const void* __restrict__ ad2,  const void* __restrict__ b2,
    float* __restrict__ xtA, float* __restrict__ xtB,
    float* __restrict__ W1t, float* __restrict__ W2f,
    float* __restrict__ vecs, float* __restrict__ h2,
    float* __restrict__ s2, float* __restrict__ d2,
    void* __restrict__ out) {
  __shared__ __align__(16) char smem[18944];
  __shared__ float wcol[128];
  cg::grid_group grid = cg::this_grid();
  const int tid = threadIdx.x;
  const int bid = blockIdx.x;
  const int bf = detect_bf16(desc1);  // uniform; held in register to P6

  // ---- P0: prep (grid-stride). planar xt, transposed W1t, W2f, vecs ----
  {
    const int total = 131072 + 16384 + 16384 + 6 * 128;
    for (int idx = bid * 512 + tid; idx < total; idx += 256 * 512) {
      if (idx < 131072) {
        int c = idx & 127, n = idx >> 7;  // reads linear in idx
        float v = (n < 512) ? load_in(desc1, idx, bf)
                            : load_in(desc2, idx - 65536, bf);
        xtA[c * 1024 + n] = v;
      } else if (idx < 147456) {
        int i = idx - 131072;             // i = k*128 + hd
        int k = i >> 7, hdd = i & 127;
        W1t[hdd * 128 + k] = load_in(W1, i, bf);
      } else if (idx < 163840) {
        W2f[idx - 147456] = load_in(W2, idx - 147456, bf);
      } else {
        int i = idx - 163840, o = i & 127;
        float v;
        if      (i < 128) v = load_in(as1, o, bf);
        else if (i < 256) v = load_in(ad1, o, bf);
        else if (i < 384) v = load_in(b1, o, bf);
        else if (i < 512) v = load_in(as2, o, bf);
        else if (i < 640) v = load_in(ad2, o, bf);
        else              v = load_in(b2, o, bf);
        vecs[i] = v;
      }
    }
  }
  grid.sync();

  layer_phase<0>(smem, wcol, xtA, xtB, W1t, vecs, bid);  // L1 inside
  grid.sync();
  layer_phase<1>(smem, wcol, xtB, xtA, W1t, vecs, bid);  // L2 cross
  grid.sync();
  layer_phase<0>(smem, wcol, xtA, xtB, W1t, vecs, bid);  // L3 inside
  grid.sync();
  layer_phase<1>(smem, wcol, xtB, xtA, W1t, vecs, bid);  // L4 cross
  grid.sync();

  // ---- P5: mm2.  4 rows/block, 128 cols; planar x reads; LDS reduce ----
  {
    float* rs = (float*)(smem);
    float* rd = (float*)(smem + 2048);
    const int row = bid * 4 + (tid >> 7);
    const int c = tid & 127;
    float acc0 = 0.f, acc1 = 0.f;
    for (int k0 = 0; k0 < 128; k0 += 8) {
      float xb[8];
#pragma unroll
      for (int u = 0; u < 8; ++u) xb[u] = xtA[(k0 + u) * 1024 + row];
#pragma unroll
      for (int u = 0; u < 8; u += 2) {
        acc0 = fmaf(xb[u],     W2f[(k0 + u) * 128 + c],     acc0);
        acc1 = fmaf(xb[u + 1], W2f[(k0 + u + 1) * 128 + c], acc1);
      }
    }
    float acc = acc0 + acc1;
    h2[row * 128 + c] = acc;
    rs[tid] = acc * vecs[384 + c];  // a_src2
    rd[tid] = acc * vecs[512 + c];  // a_dst2
    __syncthreads();
    for (int off = 64; off > 0; off >>= 1) {
      if ((tid & 127) < off) { rs[tid] += rs[tid + off]; rd[tid] += rd[tid + off]; }
      __syncthreads();
    }
    if ((tid & 127) == 0) {
      s2[row] = rs[tid];
      d2[row] = rd[tid];
    }
  }
  grid.sync();

  // ---- P6: att2.  4 dsts/block, one per 128-thread group ----
  {
    float* pT = (float*)(smem);  // pT[j*4 + ld], 2048 floats
    const int dstBase = bid * 4;
    const int srcBase = (dstBase < 512) ? 512 : 0;  // cross edges
    for (int e = tid; e < 2048; e += 512) {
      int j = e >> 2, ld = e & 3;
      float t = s2[srcBase + j] + d2[dstBase + ld];
      pT[e] = __expf(fmaxf(t, 0.2f * t));
    }
    __syncthreads();

    const int c = tid & 127;
    const int g = tid >> 7;            // 0..3 -> dst within block
    const int i0 = dstBase + g;
    float den = 0.f, num = 0.f;
    const float* hrow = h2 + srcBase * 128 + c;
    for (int j0 = 0; j0 < 512; j0 += 8) {
      float hb[8];
#pragma unroll
      for (int u = 0; u < 8; ++u) hb[u] = hrow[(j0 + u) * 128];
#pragma unroll
      for (int u = 0; u < 8; ++u) {
        float p = pT[(j0 + u) * 4 + g];
        den += p;
        num = fmaf(p, hb[u], num);
      }
    }
    // self-loop
    float ts = s2[i0] + d2[i0];
    float ps = __expf(fmaxf(ts, 0.2f * ts));
    den += ps;
    num = fmaf(ps, h2[i0 * 128 + c], num);

    float o = num / (den + 1e-16f) + vecs[640 + c];
    if (bf) ((bf16*)out)[i0 * 128 + c] = __float2bfloat16(o);
    else    ((float*)out)[i0 * 128 + c] = o;
  }
}

// ------------------------------------------------------------- launcher ----
extern "C" void kernel_launch(void* const* d_in, const int* in_sizes, int n_in,
                              void* d_out, int out_size, void* d_ws, size_t ws_size,
                              hipStream_t stream) {
  (void)in_sizes; (void)n_in; (void)out_size; (void)ws_size;
  float* ws   = (float*)d_ws;
  float* xtA  = ws;            // 131072 (planar [ch][node])
  float* xtB  = ws + 131072;   // 131072 (planar [ch][node])
  float* h2   = ws + 262144;   // 131072 (row-major)
  float* W1t  = ws + 393216;   // 16384 (transposed W1)
  float* W2f  = ws + 409600;   // 16384
  float* vecs = ws + 425984;   // 768
  float* s2   = ws + 426752;   // 1024
  float* d2   = ws + 427776;   // 1024

  void* desc1 = d_in[0]; void* desc2 = d_in[1]; void* W1 = d_in[2];
  void* as1 = d_in[3];   void* ad1 = d_in[4];   void* b1 = d_in[5];
  void* W2 = d_in[6];    void* as2 = d_in[7];   void* ad2 = d_in[8];
  void* b2 = d_in[9];

  void* args[] = {&desc1, &desc2, &W1, &as1, &ad1, &b1, &W2, &as2, &ad2, &b2,
                  &xtA, &xtB, &W1t, &W2f, &vecs, &h2, &s2, &d2, &d_out};
  hipLaunchCooperativeKernel((const void*)fused_kernel, dim3(256), dim3(512),
                             args, 0, stream);
}

// Round 9
// 194.459 us; speedup vs baseline: 3.1560x; 3.1560x over previous
//
#include <hip/hip_runtime.h>
#include <hip/hip_bf16.h>

// GAT on two 512-node cliques + bipartite cross edges, 5 GATConv layers.
//
// R22: minimum-serial-depth split (7 dispatches) with all-fast kernels.
// Series conclusion: grid-wide sync on MI355X costs ~50-90us/barrier no
// matter the implementation (R14/R18/R19/R20 hand-rolled, R21 cooperative
// runtime) -> fusion dead.  Cross-round fit: ~13us per serial dispatch
// boundary + small real work (R15 gemm~2us, bucket-attn~4us; R13's fused
// layer ~18us real due to its 160-deep uncoalesced phase-A chain).
// This round: R13's 7-dispatch shape (algorithmic minimum serial depth)
// with R20's VERIFIED fast layer body: planar coalesced phase A (per-k
// dword loads, W column in LDS) + verbatim R13 bucket softmax + planar
// write.  All phase bodies ran absmax-0.0 inside R18/R20/R21; this only
// removes barriers and re-emits phases as standalone kernels.

typedef __hip_bfloat16 bf16;

__device__ __forceinline__ float b2f(bf16 x) { return __bfloat162float(x); }

__device__ __forceinline__ int detect_bf16(const void* desc1) {
  const unsigned* u = (const unsigned*)desc1;
  int hits = 0;
#pragma unroll 8
  for (int i = 0; i < 256; ++i) {
    unsigned e = (u[i] >> 7) & 0xFFu;
    hits += (e >= 100u && e <= 140u) ? 1 : 0;
  }
  return hits >= 200 ? 1 : 0;
}

__device__ __forceinline__ float load_in(const void* p, int i, int bf) {
  return bf ? b2f(((const bf16*)p)[i]) : ((const float*)p)[i];
}

// ---------------------------------------------------------------- prep ----
// xt PLANAR: xt[c*1024 + n].  Reads perfectly linear; writes strided (tiny).
// W1t transposed: W1t[hd*128 + k] = W1[k*128 + hd].
__global__ __launch_bounds__(256) void prep_kernel(
    const void* __restrict__ desc1, const void* __restrict__ desc2,
    const void* __restrict__ W1,   const void* __restrict__ as1,
    const void* __restrict__ ad1,  const void* __restrict__ b1,
    const void* __restrict__ W2,   const void* __restrict__ as2,
    const void* __restrict__ ad2,  const void* __restrict__ b2,
    float* __restrict__ xt, float* __restrict__ W1t, float* __restrict__ W2f,
    float* __restrict__ vecs, int* __restrict__ flag) {
  const int bf = detect_bf16(desc1);
  if (blockIdx.x == 0 && threadIdx.x == 0) *flag = bf;
  const int total = 131072 + 16384 + 16384 + 6 * 128;
  for (int idx = blockIdx.x * blockDim.x + threadIdx.x; idx < total;
       idx += gridDim.x * blockDim.x) {
    if (idx < 131072) {
      int c = idx & 127, n = idx >> 7;    // reads linear in idx
      float v = (n < 512) ? load_in(desc1, idx, bf)
                          : load_in(desc2, idx - 65536, bf);
      xt[c * 1024 + n] = v;
    } else if (idx < 147456) {
      int i = idx - 131072;               // i = k*128 + hd (W1 row-major)
      int k = i >> 7, hdd = i & 127;
      W1t[hdd * 128 + k] = load_in(W1, i, bf);
    } else if (idx < 163840) {
      W2f[idx - 147456] = load_in(W2, idx - 147456, bf);
    } else {
      int i = idx - 163840, o = i & 127;
      float v;
      if      (i < 128) v = load_in(as1, o, bf);
      else if (i < 256) v = load_in(ad1, o, bf);
      else if (i < 384) v = load_in(b1, o, bf);
      else if (i < 512) v = load_in(as2, o, bf);
      else if (i < 640) v = load_in(ad2, o, bf);
      else              v = load_in(b2, o, bf);
      vecs[i] = v;
    }
  }
}

// ------------------------------------------------------------ GAT layer ----
// grid 256 = (S<<7)|hd, 512 threads.  Phase A: planar coalesced per-k dword
// loads + W column staged in LDS (FMA parity: even k->acc0, odd->acc1).
// Phase B: R13 bucket softmax VERBATIM.  Planar coalesced output write.
// Body identical to R20's layer_phase (absmax 0.0 verified in fused runs).
template <int CROSS>
__global__ __launch_bounds__(512, 2) void layer_kernel(
    const float* __restrict__ xt_in, float* __restrict__ xt_out,
    const float* __restrict__ W1t, const float* __restrict__ vecs) {
  __shared__ float    wcol[128];
  __shared__ float    sS[512];
  __shared__ float    sH[512];
  __shared__ unsigned hA[512];
  __shared__ unsigned ISb[512];
  __shared__ unsigned binNext[512];
  __shared__ float2   PRE[512];
  __shared__ float2   SUF[512];
  __shared__ float    red[16];
  __shared__ unsigned wTot[8];
  __shared__ float2   preTot[8];
  __shared__ float2   sufTot[8];

  const int tid  = threadIdx.x;
  const int lane = tid & 63;
  const int wave = tid >> 6;
  const int hd   = blockIdx.x & 127;
  const int S    = blockIdx.x >> 7;
  const int D    = CROSS ? (1 - S) : S;
  const float a_src = vecs[hd], a_dst = vecs[128 + hd], bias = vecs[256 + hd];

  // Phase A: stage W column, per-thread dot(s).
  if (tid < 32) ((float4*)wcol)[tid] = ((const float4*)(W1t + hd * 128))[tid];
  __syncthreads();
  float acc0 = 0.f, acc1 = 0.f, accD0 = 0.f, accD1 = 0.f;
  {
    const int nS = S * 512 + tid;
    const int nD = D * 512 + tid;
    for (int k0 = 0; k0 < 128; k0 += 8) {
      float xs[8], xd[8];
#pragma unroll
      for (int u = 0; u < 8; ++u) {
        xs[u] = xt_in[(k0 + u) * 1024 + nS];
        if (CROSS) xd[u] = xt_in[(k0 + u) * 1024 + nD];
      }
#pragma unroll
      for (int u = 0; u < 8; u += 2) {
        acc0 = fmaf(xs[u],     wcol[k0 + u],     acc0);
        acc1 = fmaf(xs[u + 1], wcol[k0 + u + 1], acc1);
        if (CROSS) {
          accD0 = fmaf(xd[u],     wcol[k0 + u],     accD0);
          accD1 = fmaf(xd[u + 1], wcol[k0 + u + 1], accD1);
        }
      }
    }
  }
  const float h_src = acc0 + acc1;
  const float h_dst = CROSS ? (accD0 + accD1) : h_src;
  const float s_own = h_src * a_src;
  const float d_own = h_dst * a_dst;

  // B1: block min/max of s; zero hist.
  {
    float mnw = s_own, mxw = s_own;
#pragma unroll
    for (int off = 32; off > 0; off >>= 1) {
      mnw = fminf(mnw, __shfl_down(mnw, off));
      mxw = fmaxf(mxw, __shfl_down(mxw, off));
    }
    if (lane == 0) { red[wave] = mnw; red[8 + wave] = mxw; }
  }
  hA[tid] = 0;
  binNext[tid] = 0;
  __syncthreads();                                        // (1)
  const float mn = fminf(fminf(fminf(red[0], red[1]), fminf(red[2], red[3])),
                         fminf(fminf(red[4], red[5]), fminf(red[6], red[7])));
  const float mx = fmaxf(fmaxf(fmaxf(red[8], red[9]), fmaxf(red[10], red[11])),
                         fmaxf(fmaxf(red[12], red[13]), fmaxf(red[14], red[15])));
  const float scale = 512.0f / fmaxf(mx - mn, 1e-20f);

  // B2: histogram.
  const int myBin = (int)fminf(fmaxf((s_own - mn) * scale, 0.0f), 511.0f);
  atomicAdd(&hA[myBin], 1u);
  __syncthreads();                                        // (2)

  // B3: inclusive scan of hist.
  {
    unsigned v = hA[tid];
#pragma unroll
    for (int off = 1; off < 64; off <<= 1) {
      unsigned u = __shfl_up(v, off);
      if (lane >= off) v += u;
    }
    if (lane == 63) wTot[wave] = v;
    __syncthreads();                                      // (3)
    unsigned pre = 0;
#pragma unroll
    for (int w = 0; w < 8; ++w) pre += (w < wave) ? wTot[w] : 0u;
    ISb[tid] = v + pre;
    __syncthreads();                                      // (4)
  }

  // B4: scatter into bucket order.
  {
    unsigned base = myBin ? ISb[myBin - 1] : 0u;
    unsigned pos = base + atomicAdd(&binNext[myBin], 1u);
    sS[pos] = s_own;
    sH[pos] = h_src;
  }
  __syncthreads();                                        // (5)

  // B5: prefix/suffix pairs.
  {
    const float sv = sS[tid];
    const float hv = sH[tid];
    const float e1 = __expf(sv), e2 = __expf(0.2f * sv);
    float p0 = e2, p1 = e2 * hv;
    float q0 = e1, q1 = e1 * hv;
#pragma unroll
    for (int off = 1; off < 64; off <<= 1) {
      float u0 = __shfl_up(p0, off), u1 = __shfl_up(p1, off);
      if (lane >= off) { p0 += u0; p1 += u1; }
      float v0 = __shfl_down(q0, off), v1 = __shfl_down(q1, off);
      if (lane + off < 64) { q0 += v0; q1 += v1; }
    }
    if (lane == 63) preTot[wave] = make_float2(p0, p1);
    if (lane == 0)  sufTot[wave] = make_float2(q0, q1);
    __syncthreads();                                      // (6)
    float a0 = 0.f, a1 = 0.f, b0 = 0.f, b1 = 0.f;
#pragma unroll
    for (int w = 0; w < 8; ++w) {
      float2 pt = preTot[w], st = sufTot[w];
      if (w < wave) { a0 += pt.x; a1 += pt.y; }
      if (w > wave) { b0 += st.x; b1 += st.y; }
    }
    PRE[tid] = make_float2(p0 + a0, p1 + a1);
    SUF[tid] = make_float2(q0 + b0, q1 + b1);
    __syncthreads();                                      // (7)
  }

  // B7: per destination combine.
  {
    const float theta = -d_own;
    int b = (int)fminf(fmaxf((theta - mn) * scale, 0.0f), 511.0f);
    unsigned k0 = b ? ISb[b - 1] : 0u;
    unsigned k1 = ISb[b];
    float F1 = __expf(d_own), F2 = __expf(0.2f * d_own);
    float P2 = 0.f, P2h = 0.f, S1 = 0.f, S1h = 0.f;
    if (k0 > 0)   { float2 t2 = PRE[k0 - 1]; P2 = t2.x; P2h = t2.y; }
    if (k1 < 512) { float2 t2 = SUF[k1];     S1 = t2.x; S1h = t2.y; }
    float den = F1 * S1 + F2 * P2;
    float num = F1 * S1h + F2 * P2h;
    for (unsigned e = k0; e < k1; ++e) {
      float se = sS[e], he = sH[e];
      float p = (se >= theta) ? F1 * __expf(se) : F2 * __expf(0.2f * se);
      den += p;
      num = fmaf(p, he, num);
    }
    if (CROSS) {
      float t = h_dst * a_src + d_own;
      float p = __expf(fmaxf(t, 0.2f * t));
      den += p;
      num = fmaf(p, h_dst, num);
    }
    float o = num / (den + 1e-16f) + bias;
    o = (o > 0.f) ? o : expm1f(o);  // ELU
    xt_out[hd * 1024 + D * 512 + tid] = o;  // planar, coalesced
  }
}

// ----------------------------------------------------- final layer: mm2 ----
// grid 512 x 256: 2 rows x 128 cols per block.  Planar x reads (broadcast
// per row).  Even-k -> acc0, odd-k -> acc1.  h2 row-major.
__global__ __launch_bounds__(256, 2) void mm2_kernel(
    const float* __restrict__ xt_in, const float* __restrict__ W2f,
    const float* __restrict__ vecs, float* __restrict__ h2,
    float* __restrict__ s2, float* __restrict__ d2) {
  __shared__ float rs[256], rd[256];
  const int tid = threadIdx.x;
  const int row = blockIdx.x * 2 + (tid >> 7);
  const int c = tid & 127;
  float acc0 = 0.f, acc1 = 0.f;
  for (int k0 = 0; k0 < 128; k0 += 8) {
    float xb[8];
#pragma unroll
    for (int u = 0; u < 8; ++u) xb[u] = xt_in[(k0 + u) * 1024 + row];
#pragma unroll
    for (int u = 0; u < 8; u += 2) {
      acc0 = fmaf(xb[u],     W2f[(k0 + u) * 128 + c],     acc0);
      acc1 = fmaf(xb[u + 1], W2f[(k0 + u + 1) * 128 + c], acc1);
    }
  }
  float acc = acc0 + acc1;
  h2[row * 128 + c] = acc;
  rs[tid] = acc * vecs[384 + c];  // a_src2
  rd[tid] = acc * vecs[512 + c];  // a_dst2
  __syncthreads();
  for (int off = 64; off > 0; off >>= 1) {
    if ((tid & 127) < off) { rs[tid] += rs[tid + off]; rd[tid] += rd[tid + off]; }
    __syncthreads();
  }
  if ((tid & 127) == 0) {
    s2[row] = rs[tid];
    d2[row] = rd[tid];
  }
}

// ---------------------------------------------------- final layer: attn ----
// Final conv: heads=1, ch=128, cross edges + self, no ELU, +b2.
// 512 blocks x 256 threads: 2 dsts/block.
__global__ __launch_bounds__(256, 2) void att2_kernel(
    const float* __restrict__ h2, const float* __restrict__ s2,
    const float* __restrict__ d2, const float* __restrict__ vecs,
    void* __restrict__ out, const int* __restrict__ flag) {
  __shared__ __align__(16) float pT[512 * 2];  // pT[j*2 + ld]
  const int tid = threadIdx.x;
  const int dstBase = blockIdx.x * 2;
  const int srcBase = (dstBase < 512) ? 512 : 0;  // cross edges

  for (int e = tid; e < 1024; e += 256) {
    int j = e >> 1, ld = e & 1;
    float t = s2[srcBase + j] + d2[dstBase + ld];
    pT[e] = __expf(fmaxf(t, 0.2f * t));
  }
  __syncthreads();

  const int c = tid & 127;
  const int g = tid >> 7;            // 0 or 1 -> dst within block
  const int i0 = dstBase + g;
  float den = 0.f, num = 0.f;
  const float* hrow = h2 + srcBase * 128 + c;
  for (int j0 = 0; j0 < 512; j0 += 8) {
    float hb[8];
#pragma unroll
    for (int u = 0; u < 8; ++u) hb[u] = hrow[(j0 + u) * 128];
#pragma unroll
    for (int u = 0; u < 8; ++u) {
      float p = pT[(j0 + u) * 2 + g];
      den += p;
      num = fmaf(p, hb[u], num);
    }
  }
  // self-loop
  float ts = s2[i0] + d2[i0];
  float ps = __expf(fmaxf(ts, 0.2f * ts));
  den += ps;
  num = fmaf(ps, h2[i0 * 128 + c], num);

  float o = num / (den + 1e-16f) + vecs[640 + c];
  if (*flag) ((bf16*)out)[i0 * 128 + c] = __float2bfloat16(o);
  else       ((float*)out)[i0 * 128 + c] = o;
}

// ------------------------------------------------------------- launcher ----
extern "C" void kernel_launch(void* const* d_in, const int* in_sizes, int n_in,
                              void* d_out, int out_size, void* d_ws, size_t ws_size,
                              hipStream_t stream) {
  (void)in_sizes; (void)n_in; (void)out_size; (void)ws_size;
  float* ws   = (float*)d_ws;
  float* xtA  = ws;            // 131072 (planar [ch][node])
  float* xtB  = ws + 131072;   // 131072 (planar [ch][node])
  float* h2   = ws + 262144;   // 131072 (row-major)
  float* W1t  = ws + 393216;   // 16384 (transposed W1)
  float* W2f  = ws + 409600;   // 16384
  float* vecs = ws + 425984;   // 768
  float* s2   = ws + 426752;   // 1024
  float* d2   = ws + 427776;   // 1024
  int*   flag = (int*)(ws + 428800);

  prep_kernel<<<256, 256, 0, stream>>>(d_in[0], d_in[1], d_in[2], d_in[3],
                                       d_in[4], d_in[5], d_in[6], d_in[7],
                                       d_in[8], d_in[9], xtA, W1t, W2f, vecs,
                                       flag);
  layer_kernel<0><<<256, 512, 0, stream>>>(xtA, xtB, W1t, vecs);  // L1 inside
  layer_kernel<1><<<256, 512, 0, stream>>>(xtB, xtA, W1t, vecs);  // L2 cross
  layer_kernel<0><<<256, 512, 0, stream>>>(xtA, xtB, W1t, vecs);  // L3 inside
  layer_kernel<1><<<256, 512, 0, stream>>>(xtB, xtA, W1t, vecs);  // L4 cross
  mm2_kernel<<<512, 256, 0, stream>>>(xtA, W2f, vecs, h2, s2, d2);
  att2_kernel<<<512, 256, 0, stream>>>(h2, s2, d2, vecs, d_out, flag);
}

// Round 11
// 169.219 us; speedup vs baseline: 3.6267x; 1.1492x over previous
//
#include <hip/hip_runtime.h>
#include <hip/hip_bf16.h>

// GAT on two 512-node cliques + bipartite cross edges, 5 GATConv layers.
//
// R24 = R23 resubmission with the gemm1 dtype branch hardened.
// R23 (micro-prep + raw-input L1 GEMM) core-dumped in pytest with no
// counters; a full bounds/layout audit found no fault (f32 path reads
// exactly 256KB, bf16 exactly 128KB, flag is stream-ordered), and the
// harness has shown infra-level failures before (R19).  Resubmitting the
// same design with the only code-level suspect removed: gemm1's runtime
// dual-dtype branch is now a scalar (readfirstlane) branch selecting two
// fully self-contained loops -- no shared register state, untaken path's
// address math never formed.  All else identical to R23: micro-prep
// (W1t/W2f/vecs/flag only, 33K elems); gemm L2-L4 / attn / mm2 / att2
// VERBATIM R15 (166.2us, absmax 0.0 verified).

typedef __hip_bfloat16 bf16;

__device__ __forceinline__ float b2f(bf16 x) { return __bfloat162float(x); }

__device__ __forceinline__ int detect_bf16(const void* desc1) {
  const unsigned* u = (const unsigned*)desc1;
  int hits = 0;
#pragma unroll 8
  for (int i = 0; i < 256; ++i) {
    unsigned e = (u[i] >> 7) & 0xFFu;
    hits += (e >= 100u && e <= 140u) ? 1 : 0;
  }
  return hits >= 200 ? 1 : 0;
}

__device__ __forceinline__ float load_in(const void* p, int i, int bf) {
  return bf ? b2f(((const bf16*)p)[i]) : ((const float*)p)[i];
}

// ---------------------------------------------------------------- prep ----
// Micro-prep: only W1t (transposed W1), W2f, vecs, flag.  33K elems.
__global__ __launch_bounds__(256) void prep_kernel(
    const void* __restrict__ desc1,
    const void* __restrict__ W1,   const void* __restrict__ as1,
    const void* __restrict__ ad1,  const void* __restrict__ b1,
    const void* __restrict__ W2,   const void* __restrict__ as2,
    const void* __restrict__ ad2,  const void* __restrict__ b2,
    float* __restrict__ W1t, float* __restrict__ W2f,
    float* __restrict__ vecs, int* __restrict__ flag) {
  const int bf = detect_bf16(desc1);
  if (blockIdx.x == 0 && threadIdx.x == 0) *flag = bf;
  const int total = 16384 + 16384 + 6 * 128;
  for (int idx = blockIdx.x * blockDim.x + threadIdx.x; idx < total;
       idx += gridDim.x * blockDim.x) {
    if (idx < 16384) {
      int k = idx >> 7, hdd = idx & 127;   // W1 row-major read, coalesced
      W1t[hdd * 128 + k] = load_in(W1, idx, bf);
    } else if (idx < 32768) {
      W2f[idx - 16384] = load_in(W2, idx - 16384, bf);
    } else {
      int i = idx - 32768, o = i & 127;
      float v;
      if      (i < 128) v = load_in(as1, o, bf);
      else if (i < 256) v = load_in(ad1, o, bf);
      else if (i < 384) v = load_in(b1, o, bf);
      else if (i < 512) v = load_in(as2, o, bf);
      else if (i < 640) v = load_in(ad2, o, bf);
      else              v = load_in(b2, o, bf);
      vecs[i] = v;
    }
  }
}

// --------------------------------------------------------- L1 GEMM (raw) ----
// Ht[hd*1024+node] = dot(x[node,:], W1[:,hd]) reading RAW inputs.
// Scalar (readfirstlane) dtype branch; two self-contained loops.
// f32: 32 contiguous float4 per row.  bf16: 16 contiguous uint4 (8 bf16),
// shift-convert (== __bfloat162float exactly).  FMA parity (even k->acc0,
// odd->acc1) and ascending-k order identical to gemm_kernel -> bit-exact.
__global__ __launch_bounds__(256, 2) void gemm1_kernel(
    const void* __restrict__ desc1, const void* __restrict__ desc2,
    const float* __restrict__ W1t, const int* __restrict__ flag,
    float* __restrict__ Ht) {
  __shared__ float wcol[128];
  const int tid = threadIdx.x;
  const int hd = blockIdx.x & 127;
  const int chunk = blockIdx.x >> 7;
  const int node = chunk * 256 + tid;
  if (tid < 32) ((float4*)wcol)[tid] = ((const float4*)(W1t + hd * 128))[tid];
  __syncthreads();
  const int bf = __builtin_amdgcn_readfirstlane(*flag);  // scalar branch
  const int row = node & 511;
  const void* base = (node < 512) ? desc1 : desc2;
  float out;
  if (!bf) {
    const float4* x4 = (const float4*)base + row * 32;
    float acc0 = 0.f, acc1 = 0.f;
    for (int cc = 0; cc < 32; cc += 8) {
      float4 xs[8];
#pragma unroll
      for (int u = 0; u < 8; ++u) xs[u] = x4[cc + u];
#pragma unroll
      for (int u = 0; u < 8; ++u) {
        const int k = (cc + u) * 4;
        acc0 = fmaf(xs[u].x, wcol[k],     acc0);
        acc1 = fmaf(xs[u].y, wcol[k + 1], acc1);
        acc0 = fmaf(xs[u].z, wcol[k + 2], acc0);
        acc1 = fmaf(xs[u].w, wcol[k + 3], acc1);
      }
    }
    out = acc0 + acc1;
  } else {
    const uint4* xu = (const uint4*)base + row * 16;
    float acc0 = 0.f, acc1 = 0.f;
    for (int cc = 0; cc < 16; cc += 8) {
      uint4 q[8];
#pragma unroll
      for (int u = 0; u < 8; ++u) q[u] = xu[cc + u];
#pragma unroll
      for (int u = 0; u < 8; ++u) {
        const int k = (cc + u) * 8;
        const unsigned w0 = q[u].x, w1 = q[u].y, w2 = q[u].z, w3 = q[u].w;
        acc0 = fmaf(__uint_as_float(w0 << 16),          wcol[k],     acc0);
        acc1 = fmaf(__uint_as_float(w0 & 0xFFFF0000u),  wcol[k + 1], acc1);
        acc0 = fmaf(__uint_as_float(w1 << 16),          wcol[k + 2], acc0);
        acc1 = fmaf(__uint_as_float(w1 & 0xFFFF0000u),  wcol[k + 3], acc1);
        acc0 = fmaf(__uint_as_float(w2 << 16),          wcol[k + 4], acc0);
        acc1 = fmaf(__uint_as_float(w2 & 0xFFFF0000u),  wcol[k + 5], acc1);
        acc0 = fmaf(__uint_as_float(w3 << 16),          wcol[k + 6], acc0);
        acc1 = fmaf(__uint_as_float(w3 & 0xFFFF0000u),  wcol[k + 7], acc1);
      }
    }
    out = acc0 + acc1;
  }
  Ht[hd * 1024 + node] = out;
}

// ------------------------------------------------- layer GEMM (packed xt) ----
// VERBATIM R15.  Ht[hd*1024+node] = dot(x[node,:], W1[:,hd]); packed xt.
__global__ __launch_bounds__(256, 2) void gemm_kernel(
    const float* __restrict__ xt_in, const float* __restrict__ W1t,
    float* __restrict__ Ht) {
  __shared__ float wcol[128];
  const int tid = threadIdx.x;
  const int hd = blockIdx.x & 127;
  const int chunk = blockIdx.x >> 7;
  const int node = chunk * 256 + tid;
  if (tid < 32) ((float4*)wcol)[tid] = ((const float4*)(W1t + hd * 128))[tid];
  __syncthreads();
  const float4* x4 = (const float4*)xt_in;
  float acc0 = 0.f, acc1 = 0.f;
  for (int cc = 0; cc < 32; cc += 8) {
    float4 xs[8];
#pragma unroll
    for (int u = 0; u < 8; ++u) xs[u] = x4[(cc + u) * 1024 + node];
#pragma unroll
    for (int u = 0; u < 8; ++u) {
      const int k = (cc + u) * 4;
      acc0 = fmaf(xs[u].x, wcol[k],     acc0);
      acc1 = fmaf(xs[u].y, wcol[k + 1], acc1);
      acc0 = fmaf(xs[u].z, wcol[k + 2], acc0);
      acc1 = fmaf(xs[u].w, wcol[k + 3], acc1);
    }
  }
  Ht[hd * 1024 + node] = acc0 + acc1;
}

// ------------------------------------------------------------ layer attn ----
// VERBATIM R15.  grid 256 = (S<<7)|hd, 512 threads; bucket softmax;
// packed xt_out write.
template <int CROSS>
__global__ __launch_bounds__(512, 2) void attn_kernel(
    const float* __restrict__ Ht, float* __restrict__ xt_out,
    const float* __restrict__ vecs) {
  __shared__ float    sS[512];
  __shared__ float    sH[512];
  __shared__ unsigned hA[512];
  __shared__ unsigned ISb[512];
  __shared__ unsigned binNext[512];
  __shared__ float2   PRE[512];
  __shared__ float2   SUF[512];
  __shared__ float    red[16];
  __shared__ unsigned wTot[8];
  __shared__ float2   preTot[8];
  __shared__ float2   sufTot[8];

  const int tid  = threadIdx.x;
  const int lane = tid & 63;
  const int wave = tid >> 6;
  const int hd   = blockIdx.x & 127;
  const int S    = blockIdx.x >> 7;
  const int D    = CROSS ? (1 - S) : S;
  const float a_src = vecs[hd], a_dst = vecs[128 + hd], bias = vecs[256 + hd];

  const float h_src = Ht[hd * 1024 + S * 512 + tid];
  const float h_dst = CROSS ? Ht[hd * 1024 + D * 512 + tid] : h_src;
  const float s_own = h_src * a_src;
  const float d_own = h_dst * a_dst;

  // B1: block min/max of s; zero hist.
  {
    float mnw = s_own, mxw = s_own;
#pragma unroll
    for (int off = 32; off > 0; off >>= 1) {
      mnw = fminf(mnw, __shfl_down(mnw, off));
      mxw = fmaxf(mxw, __shfl_down(mxw, off));
    }
    if (lane == 0) { red[wave] = mnw; red[8 + wave] = mxw; }
  }
  hA[tid] = 0;
  binNext[tid] = 0;
  __syncthreads();                                        // (1)
  const float mn = fminf(fminf(fminf(red[0], red[1]), fminf(red[2], red[3])),
                         fminf(fminf(red[4], red[5]), fminf(red[6], red[7])));
  const float mx = fmaxf(fmaxf(fmaxf(red[8], red[9]), fmaxf(red[10], red[11])),
                         fmaxf(fmaxf(red[12], red[13]), fmaxf(red[14], red[15])));
  const float scale = 512.0f / fmaxf(mx - mn, 1e-20f);

  // B2: histogram.
  const int myBin = (int)fminf(fmaxf((s_own - mn) * scale, 0.0f), 511.0f);
  atomicAdd(&hA[myBin], 1u);
  __syncthreads();                                        // (2)

  // B3: inclusive scan of hist.
  {
    unsigned v = hA[tid];
#pragma unroll
    for (int off = 1; off < 64; off <<= 1) {
      unsigned u = __shfl_up(v, off);
      if (lane >= off) v += u;
    }
    if (lane == 63) wTot[wave] = v;
    __syncthreads();                                      // (3)
    unsigned pre = 0;
#pragma unroll
    for (int w = 0; w < 8; ++w) pre += (w < wave) ? wTot[w] : 0u;
    ISb[tid] = v + pre;
    __syncthreads();                                      // (4)
  }

  // B4: scatter into bucket order.
  {
    unsigned base = myBin ? ISb[myBin - 1] : 0u;
    unsigned pos = base + atomicAdd(&binNext[myBin], 1u);
    sS[pos] = s_own;
    sH[pos] = h_src;
  }
  __syncthreads();                                        // (5)

  // B5: prefix/suffix pairs.
  {
    const float sv = sS[tid];
    const float hv = sH[tid];
    const float e1 = __expf(sv), e2 = __expf(0.2f * sv);
    float p0 = e2, p1 = e2 * hv;
    float q0 = e1, q1 = e1 * hv;
#pragma unroll
    for (int off = 1; off < 64; off <<= 1) {
      float u0 = __shfl_up(p0, off), u1 = __shfl_up(p1, off);
      if (lane >= off) { p0 += u0; p1 += u1; }
      float v0 = __shfl_down(q0, off), v1 = __shfl_down(q1, off);
      if (lane + off < 64) { q0 += v0; q1 += v1; }
    }
    if (lane == 63) preTot[wave] = make_float2(p0, p1);
    if (lane == 0)  sufTot[wave] = make_float2(q0, q1);
    __syncthreads();                                      // (6)
    float a0 = 0.f, a1 = 0.f, b0 = 0.f, b1 = 0.f;
#pragma unroll
    for (int w = 0; w < 8; ++w) {
      float2 pt = preTot[w], st = sufTot[w];
      if (w < wave) { a0 += pt.x; a1 += pt.y; }
      if (w > wave) { b0 += st.x; b1 += st.y; }
    }
    PRE[tid] = make_float2(p0 + a0, p1 + a1);
    SUF[tid] = make_float2(q0 + b0, q1 + b1);
    __syncthreads();                                      // (7)
  }

  // B7: per destination combine.
  {
    const float theta = -d_own;
    int b = (int)fminf(fmaxf((theta - mn) * scale, 0.0f), 511.0f);
    unsigned k0 = b ? ISb[b - 1] : 0u;
    unsigned k1 = ISb[b];
    float F1 = __expf(d_own), F2 = __expf(0.2f * d_own);
    float P2 = 0.f, P2h = 0.f, S1 = 0.f, S1h = 0.f;
    if (k0 > 0)   { float2 t2 = PRE[k0 - 1]; P2 = t2.x; P2h = t2.y; }
    if (k1 < 512) { float2 t2 = SUF[k1];     S1 = t2.x; S1h = t2.y; }
    float den = F1 * S1 + F2 * P2;
    float num = F1 * S1h + F2 * P2h;
    for (unsigned e = k0; e < k1; ++e) {
      float se = sS[e], he = sH[e];
      float p = (se >= theta) ? F1 * __expf(se) : F2 * __expf(0.2f * se);
      den += p;
      num = fmaf(p, he, num);
    }
    if (CROSS) {
      float t = h_dst * a_src + d_own;
      float p = __expf(fmaxf(t, 0.2f * t));
      den += p;
      num = fmaf(p, h_dst, num);
    }
    float o = num / (den + 1e-16f) + bias;
    o = (o > 0.f) ? o : expm1f(o);  // ELU
    // packed layout: xt_out[((hd>>2)*1024 + node)*4 + (hd&3)]
    xt_out[(((hd >> 2) * 1024) + D * 512 + tid) * 4 + (hd & 3)] = o;
  }
}

// ----------------------------------------------------- final layer: mm2 ----
// VERBATIM R15.  grid 512 x 256: 2 rows x 128 cols per block.
__global__ __launch_bounds__(256, 2) void mm2_kernel(
    const float* __restrict__ xt_in, const float* __restrict__ W2f,
    const float* __restrict__ vecs, float* __restrict__ h2,
    float* __restrict__ s2, float* __restrict__ d2) {
  __shared__ float rs[256], rd[256];
  const int tid = threadIdx.x;
  const int row = blockIdx.x * 2 + (tid >> 7);
  const int c = tid & 127;
  float acc0 = 0.f, acc1 = 0.f;
  {
    const float4* x4 = (const float4*)xt_in;
    for (int cc = 0; cc < 32; cc += 8) {
      float4 xb[8];
#pragma unroll
      for (int u = 0; u < 8; ++u) xb[u] = x4[(cc + u) * 1024 + row];
#pragma unroll
      for (int u = 0; u < 8; ++u) {
        const int k = (cc + u) * 4;
        acc0 = fmaf(xb[u].x, W2f[k * 128 + c],       acc0);
        acc1 = fmaf(xb[u].y, W2f[(k + 1) * 128 + c], acc1);
        acc0 = fmaf(xb[u].z, W2f[(k + 2) * 128 + c], acc0);
        acc1 = fmaf(xb[u].w, W2f[(k + 3) * 128 + c], acc1);
      }
    }
  }
  float acc = acc0 + acc1;
  h2[row * 128 + c] = acc;
  rs[tid] = acc * vecs[384 + c];  // a_src2
  rd[tid] = acc * vecs[512 + c];  // a_dst2
  __syncthreads();
  for (int off = 64; off > 0; off >>= 1) {
    if ((tid & 127) < off) { rs[tid] += rs[tid + off]; rd[tid] += rd[tid + off]; }
    __syncthreads();
  }
  if ((tid & 127) == 0) {
    s2[row] = rs[tid];
    d2[row] = rd[tid];
  }
}

// ---------------------------------------------------- final layer: attn ----
// VERBATIM R15.  512 blocks x 256 threads: 2 dsts/block.
__global__ __launch_bounds__(256, 2) void att2_kernel(
    const float* __restrict__ h2, const float* __restrict__ s2,
    const float* __restrict__ d2, const float* __restrict__ vecs,
    void* __restrict__ out, const int* __restrict__ flag) {
  __shared__ __align__(16) float pT[512 * 2];  // pT[j*2 + ld]
  const int tid = threadIdx.x;
  const int dstBase = blockIdx.x * 2;
  const int srcBase = (dstBase < 512) ? 512 : 0;  // cross edges

  for (int e = tid; e < 1024; e += 256) {
    int j = e >> 1, ld = e & 1;
    float t = s2[srcBase + j] + d2[dstBase + ld];
    pT[e] = __expf(fmaxf(t, 0.2f * t));
  }
  __syncthreads();

  const int c = tid & 127;
  const int g = tid >> 7;            // 0 or 1 -> dst within block
  const int i0 = dstBase + g;
  float den = 0.f, num = 0.f;
  const float* hrow = h2 + srcBase * 128 + c;
  for (int j0 = 0; j0 < 512; j0 += 8) {
    float hb[8];
#pragma unroll
    for (int u = 0; u < 8; ++u) hb[u] = hrow[(j0 + u) * 128];
#pragma unroll
    for (int u = 0; u < 8; ++u) {
      float p = pT[(j0 + u) * 2 + g];
      den += p;
      num = fmaf(p, hb[u], num);
    }
  }
  // self-loop
  float ts = s2[i0] + d2[i0];
  float ps = __expf(fmaxf(ts, 0.2f * ts));
  den += ps;
  num = fmaf(ps, h2[i0 * 128 + c], num);

  float o = num / (den + 1e-16f) + vecs[640 + c];
  if (*flag) ((bf16*)out)[i0 * 128 + c] = __float2bfloat16(o);
  else       ((float*)out)[i0 * 128 + c] = o;
}

// ------------------------------------------------------------- launcher ----
extern "C" void kernel_launch(void* const* d_in, const int* in_sizes, int n_in,
                              void* d_out, int out_size, void* d_ws, size_t ws_size,
                              hipStream_t stream) {
  (void)in_sizes; (void)n_in; (void)out_size; (void)ws_size;
  float* ws   = (float*)d_ws;
  float* xtA  = ws;            // 131072 (packed float4 layout)
  float* xtB  = ws + 131072;   // 131072 (packed float4 layout)
  float* h2   = ws + 262144;   // 131072 (row-major); ALSO aliased as Ht
  float* Ht   = h2;            // Ht[hd*1024+node]; dead once mm2 runs
  float* W1t  = ws + 393216;   // 16384 (transposed W1)
  float* W2f  = ws + 409600;   // 16384
  float* vecs = ws + 425984;   // 768
  float* s2   = ws + 426752;   // 1024
  float* d2   = ws + 427776;   // 1024
  int*   flag = (int*)(ws + 428800);

  prep_kernel<<<64, 256, 0, stream>>>(d_in[0], d_in[2], d_in[3], d_in[4],
                                      d_in[5], d_in[6], d_in[7], d_in[8],
                                      d_in[9], W1t, W2f, vecs, flag);
  // L1 inside (gemm reads raw inputs)
  gemm1_kernel<<<512, 256, 0, stream>>>(d_in[0], d_in[1], W1t, flag, Ht);
  attn_kernel<0><<<256, 512, 0, stream>>>(Ht, xtB, vecs);
  // L2 cross
  gemm_kernel<<<512, 256, 0, stream>>>(xtB, W1t, Ht);
  attn_kernel<1><<<256, 512, 0, stream>>>(Ht, xtA, vecs);
  // L3 inside
  gemm_kernel<<<512, 256, 0, stream>>>(xtA, W1t, Ht);
  attn_kernel<0><<<256, 512, 0, stream>>>(Ht, xtB, vecs);
  // L4 cross
  gemm_kernel<<<512, 256, 0, stream>>>(xtB, W1t, Ht);
  attn_kernel<1><<<256, 512, 0, stream>>>(Ht, xtA, vecs);
  // final layer
  mm2_kernel<<<512, 256, 0, stream>>>(xtA, W2f, vecs, h2, s2, d2);
  att2_kernel<<<512, 256, 0, stream>>>(h2, s2, d2, vecs, d_out, flag);
}